// Round 1
// 194.324 us; speedup vs baseline: 1.0017x; 1.0017x over previous
//
#include <hip/hip_runtime.h>
#include <math.h>

#define K_POLY   20000
#define PMAX     30
#define NUM_PTS  5
#define C_MID    112
#define C_OUT    224
#define PE_DIM   32
#define GEO_DIM  256
#define M_ROWS   (K_POLY*NUM_PTS)        // 100000

#define NTILES   14                      // 224/16 n-tiles
#define KSTEPS   11                      // K padded 336 -> 352 = 11*32
#define WP_ELEMS (KSTEPS*NTILES*64*8)    // 78848 bf16 = 157696 B
#define NPACK_BLK ((WP_ELEMS+255)/256)   // 308
#define POLY_PER_BLK 4
#define NPREP_BLK ((K_POLY+POLY_PER_BLK-1)/POLY_PER_BLK)  // 5000

// in-place A storage: per-poly chunk of 7*112 bf16 (+16 pad) living in the
// cols-32..255 region of that poly's 5 output rows (overwritten later by LN)
#define CHUNK_STRIDE 2560    // ushort elems per poly block (5 rows * 256 * 2)
#define CHUNK_OFF    64      // ushort offset of chunk start (row 0, col 32)

#define ROWS_W   30                      // stored rows per wave (6 whole polys)
#define WAVES_B  4
#define NWAVES2  ((M_ROWS+ROWS_W-1)/ROWS_W)     // 3334
#define NBLK2    ((NWAVES2+WAVES_B-1)/WAVES_B)  // 834

typedef __attribute__((ext_vector_type(8))) short short8;
typedef __attribute__((ext_vector_type(4))) float f32x4;

__device__ inline unsigned short f2bf(float f) {
    union { float f; unsigned u; } v; v.f = f;
    return (unsigned short)((v.u + 0x7fffu + ((v.u >> 16) & 1u)) >> 16);
}

#define GLDS(gp, lp) __builtin_amdgcn_global_load_lds( \
    (const __attribute__((address_space(1))) void*)(gp), \
    (__attribute__((address_space(3))) void*)(lp), 16, 0, 0)

// ---- kernel 1: w2 pack (blocks [0,308)) + per-wave poly prep (rest) ----
__global__ __launch_bounds__(256) void prep_pack(
    const float* __restrict__ geoms, const int* __restrict__ lengths,
    const float* __restrict__ w1, const float* __restrict__ b1,
    const float* __restrict__ w2,
    const int* __restrict__ roi_w, const int* __restrict__ roi_h,
    unsigned short* __restrict__ Wp, float* __restrict__ out)
{
    if (blockIdx.x < NPACK_BLK) {
        int i = blockIdx.x * 256 + threadIdx.x;
        if (i < WP_ELEMS) {
            int j    = i & 7;
            int lane = (i >> 3) & 63;
            int grp  = i >> 9;               // ks*14 + nt
            int nt   = grp % NTILES;
            int ks   = grp / NTILES;
            int k    = ks * 32 + (lane >> 4) * 8 + j;   // k = dk*112 + c
            int n    = nt * 16 + (lane & 15);
            float v = 0.f;
            if (k < 336) {
                int dk = k / C_MID, c = k - dk * C_MID;
                v = w2[(n * C_MID + c) * 3 + dk];
            }
            Wp[i] = f2bf(v);
        }
        return;
    }

    const int poly = (blockIdx.x - NPACK_BLK) * POLY_PER_BLK + (threadIdx.x >> 6);
    const int lane = threadIdx.x & 63;
    if (poly >= K_POLY) return;

    // ---- load polyline: one point per lane ----
    const float* gp = geoms + (size_t)poly * (PMAX * 2);
    float px = 0.f, py = 0.f;
    if (lane < PMAX) { float2 p = ((const float2*)gp)[lane]; px = p.x; py = p.y; }
    const int L = lengths[poly];

    // ---- per-lane segment length, shfl prefix-scan for cum ----
    float nx = __shfl(px, lane + 1);
    float ny = __shfl(py, lane + 1);
    float seg = 0.f;
    if (lane < L - 1 && lane < PMAX - 1) {
        float dx = nx - px, dy = ny - py;
        float sq = dx * dx + dy * dy;
        seg = (sq > 0.f) ? sqrtf(sq) : 0.f;
    }
    float incl = seg;
    #pragma unroll
    for (int d = 1; d < 32; d <<= 1) {
        float v = __shfl_up(incl, d, 32);
        if ((lane & 31) >= d) incl += v;
    }
    float cum = __shfl_up(incl, 1, 32);   // cum[i] = sum seg[0..i-1]
    if ((lane & 31) == 0) cum = 0.f;
    const float total = __shfl(incl, PMAX - 2);

    const float roiw = (float)roi_w[0], roih = (float)roi_h[0];
    const float halfx = roiw * 0.5f, halfy = roih * 0.5f;
    const bool degen = total < 1e-6f;
    const float x0g = __shfl(px, 0), y0g = __shfl(py, 0);

    // ---- resample 5 points, wave-uniform via ballot searchsorted ----
    float bxv[NUM_PTS], byv[NUM_PTS];
    #pragma unroll
    for (int j = 0; j < NUM_PTS; ++j) {
        float tj = total * (0.25f * (float)j);
        unsigned long long mlt = __ballot(lane < PMAX && cum < tj);
        int idx = (int)__popcll(mlt);     // first i with cum[i] >= tj
        idx = max(1, min(idx, L - 1));
        float c1 = __shfl(cum, idx - 1);
        float s1 = __shfl(seg, idx - 1);
        float ax = __shfl(px, idx - 1), ay = __shfl(py, idx - 1);
        float bx2 = __shfl(px, idx),    by2 = __shfl(py, idx);
        float tt = (tj - c1) / (s1 + 1e-8f);
        float fx = degen ? x0g : ax + tt * (bx2 - ax);
        float fy = degen ? y0g : ay + tt * (by2 - ay);
        bxv[j] = (fx + halfx) / roiw;
        byv[j] = (fy + halfy) / roih;
    }
    if (lane == 0) {
        float* co = out + (size_t)M_ROWS * GEO_DIM + (size_t)poly * (NUM_PTS * 2);
        #pragma unroll
        for (int j = 0; j < NUM_PTS; ++j) { co[2 * j] = bxv[j]; co[2 * j + 1] = byv[j]; }
    }

    // ---- A chunk: zero halo slots + K-pad, then conv1 (one channel/lane) ----
    unsigned short* chunk = (unsigned short*)out + (size_t)poly * CHUNK_STRIDE + CHUNK_OFF;
    unsigned int* cz = (unsigned int*)chunk;
    if (lane < 56) cz[lane] = 0u;          // slot 0 (elems 0..111)
    cz[336 + lane] = 0u;                   // elems 672..799 (slot 6 + K-pad)

    #pragma unroll
    for (int it = 0; it < 2; ++it) {
        int c = it * 64 + lane;
        if (c < C_MID) {
            const float* w = w1 + c * 6;
            float w0 = w[0], wa = w[1], wb = w[2], w3 = w[3], w4 = w[4], w5 = w[5];
            float bb = b1[c];
            #pragma unroll
            for (int p = 0; p < NUM_PTS; ++p) {
                float acc = bb + bxv[p] * wa + byv[p] * w4;
                if (p > 0)           acc += bxv[p - 1] * w0 + byv[p - 1] * w3;
                if (p < NUM_PTS - 1) acc += bxv[p + 1] * wb + byv[p + 1] * w5;
                chunk[(p + 1) * C_MID + c] = f2bf(fmaxf(acc, 0.f));
            }
        }
    }
}

// ---- kernel 2: MFMA conv2 (B dbuf in LDS, 32 rows/wave) + PE + LN + store ----
__global__ __launch_bounds__(256, 3) void gemm2(
    const unsigned short* __restrict__ Wp,
    const float* __restrict__ b2, const float* __restrict__ gamma,
    const float* __restrict__ beta, float* __restrict__ out)
{
    __shared__ __align__(16) unsigned short s_B[2][NTILES * 512];  // 2 x 14336 B

    const int t = threadIdx.x, lane = t & 63, wave = t >> 6;
    const int quad = lane >> 4, m = lane & 15;
    const int rw = (blockIdx.x * WAVES_B + wave) * ROWS_W;

    // A frag bases (rows rw+m and rw+16+m; clamped rows' C output never stored)
    int r0 = min(rw + m, M_ROWS - 1);
    int r1 = min(rw + 16 + m, M_ROWS - 1);
    int poly0 = r0 / 5, p0 = r0 - poly0 * 5;
    int poly1 = r1 / 5, p1 = r1 - poly1 * 5;
    const unsigned short* A = (const unsigned short*)out;
    const unsigned short* Ab0 = A + (size_t)poly0 * CHUNK_STRIDE + CHUNK_OFF + p0 * C_MID + quad * 8;
    const unsigned short* Ab1 = A + (size_t)poly1 * CHUNK_STRIDE + CHUNK_OFF + p1 * C_MID + quad * 8;

    f32x4 acc0[NTILES], acc1[NTILES];
    #pragma unroll
    for (int nt = 0; nt < NTILES; ++nt)
        #pragma unroll
        for (int i = 0; i < 4; ++i) { acc0[nt][i] = 0.f; acc1[nt][i] = 0.f; }

    const char* WpB = (const char*)Wp;
    // prologue: stage ks=0 into buf 0 (wave w stages segments w, w+4, w+8, w+12)
    #pragma unroll
    for (int j = 0; j < 4; ++j) {
        int sgi = j * WAVES_B + wave;
        if (sgi < NTILES)
            GLDS(WpB + sgi * 1024 + lane * 16, (char*)&s_B[0][0] + sgi * 1024);
    }
    short8 a0 = *(const short8*)Ab0;
    short8 a1 = *(const short8*)Ab1;
    __syncthreads();

    int buf = 0;
    for (int ks = 0; ks < KSTEPS; ++ks) {
        short8 a0n = a0, a1n = a1;
        if (ks < KSTEPS - 1) {
            const char* src = WpB + (size_t)(ks + 1) * (NTILES * 1024);
            #pragma unroll
            for (int j = 0; j < 4; ++j) {
                int sgi = j * WAVES_B + wave;
                if (sgi < NTILES)
                    GLDS(src + sgi * 1024 + lane * 16, (char*)&s_B[buf ^ 1][0] + sgi * 1024);
            }
            a0n = *(const short8*)(Ab0 + (ks + 1) * 32);
            a1n = *(const short8*)(Ab1 + (ks + 1) * 32);
        }
        const unsigned short* bp = &s_B[buf][lane * 8];
        #pragma unroll
        for (int nt = 0; nt < NTILES; ++nt) {
            short8 b = *(const short8*)(bp + nt * 512);
            acc0[nt] = __builtin_amdgcn_mfma_f32_16x16x32_bf16(a0, b, acc0[nt], 0, 0, 0);
            acc1[nt] = __builtin_amdgcn_mfma_f32_16x16x32_bf16(a1, b, acc1[nt], 0, 0, 0);
        }
        __syncthreads();   // drains stage + a-prefetch; next buffer ready
        buf ^= 1; a0 = a0n; a1 = a1n;
    }

    // ---- PE: cols 0..31 for rows rw..rw+29 (coords from prep) ----
    {
        const float* cptr = out + (size_t)M_ROWS * GEO_DIM;
        const int col = lane & 31;
        const int d = col >> 4, isc = (col >> 3) & 1, fr = col & 7;
        const float pef = (float)(1 << fr) * 3.14159265358979323846f;
        #pragma unroll
        for (int it = 0; it < 15; ++it) {
            int r = rw + it * 2 + (lane >> 5);
            if (r < M_ROWS) {
                float x = cptr[(size_t)r * 2 + d];
                float arg = x * pef;
                out[(size_t)r * GEO_DIM + col] = isc ? __cosf(arg) : __sinf(arg);
            }
        }
    }

    // ---- bias + ReLU + in-wave LayerNorm + store cols 32..255 ----
    float bias[NTILES], gm[NTILES], bt[NTILES];
    #pragma unroll
    for (int nt = 0; nt < NTILES; ++nt) {
        int col = nt * 16 + m;
        bias[nt] = b2[col]; gm[nt] = gamma[col]; bt[nt] = beta[col];
    }

    auto epilogue = [&](f32x4 (&acc)[NTILES], int g) {
        #pragma unroll
        for (int i = 0; i < 4; ++i) {
            float s = 0.f, q = 0.f;
            #pragma unroll
            for (int nt = 0; nt < NTILES; ++nt) {
                float v = fmaxf(acc[nt][i] + bias[nt], 0.f);
                acc[nt][i] = v;
                s += v; q += v * v;
            }
            #pragma unroll
            for (int mk = 8; mk >= 1; mk >>= 1) {
                s += __shfl_xor(s, mk, 64);
                q += __shfl_xor(q, mk, 64);
            }
            float mu  = s * (1.f / C_OUT);
            float var = fmaxf(q * (1.f / C_OUT) - mu * mu, 0.f);
            float rs  = rsqrtf(var + 1e-5f);
            int r = rw + g * 16 + quad * 4 + i;
            // rows rw+30/31 (g==1, quad==3, i>=2) are the neighbor-poly garbage frag
            if (r < M_ROWS && !(g == 1 && quad == 3 && i >= 2)) {
                size_t ob = (size_t)r * GEO_DIM + PE_DIM + m;
                #pragma unroll
                for (int nt = 0; nt < NTILES; ++nt)
                    out[ob + nt * 16] = (acc[nt][i] - mu) * rs * gm[nt] + bt[nt];
            }
        }
    };
    epilogue(acc0, 0);
    epilogue(acc1, 1);
}

extern "C" void kernel_launch(void* const* d_in, const int* in_sizes, int n_in,
                              void* d_out, int out_size, void* d_ws, size_t ws_size,
                              hipStream_t stream) {
    const float* geoms   = (const float*)d_in[0];
    const int*   lengths = (const int*)d_in[1];
    const float* w1      = (const float*)d_in[2];
    const float* b1      = (const float*)d_in[3];
    const float* w2      = (const float*)d_in[4];
    const float* b2      = (const float*)d_in[5];
    const float* gamma   = (const float*)d_in[6];
    const float* beta    = (const float*)d_in[7];
    const int*   roi_w   = (const int*)d_in[8];
    const int*   roi_h   = (const int*)d_in[9];
    float* out = (float*)d_out;
    unsigned short* Wp = (unsigned short*)d_ws;   // 157696 B

    hipLaunchKernelGGL(prep_pack, dim3(NPACK_BLK + NPREP_BLK), dim3(256), 0, stream,
                       geoms, lengths, w1, b1, w2, roi_w, roi_h, Wp, out);
    hipLaunchKernelGGL(gemm2, dim3(NBLK2), dim3(256), 0, stream, Wp, b2, gamma, beta, out);
}

// Round 2
// 178.118 us; speedup vs baseline: 1.0928x; 1.0910x over previous
//
#include <hip/hip_runtime.h>
#include <math.h>

#define K_POLY   20000
#define PMAX     30
#define NUM_PTS  5
#define C_MID    112
#define C_OUT    224
#define PE_DIM   32
#define GEO_DIM  256
#define M_ROWS   (K_POLY*NUM_PTS)        // 100000

#define NTILES   14                      // 224/16 n-tiles
#define KSTEPS   11                      // K padded 336 -> 352 = 11*32
#define WP_ELEMS (KSTEPS*NTILES*64*8)    // 78848 bf16 = 157696 B
#define NPACK_BLK ((WP_ELEMS+255)/256)   // 308
#define POLY_PER_BLK 4
#define NPREP_BLK ((K_POLY+POLY_PER_BLK-1)/POLY_PER_BLK)  // 5000

// in-place A storage: per-poly chunk of 7*112 bf16 (+16 pad) living in the
// cols-32..255 region of that poly's 5 output rows (overwritten later by LN)
#define CHUNK_STRIDE 2560    // ushort elems per poly block (5 rows * 256 * 2)
#define CHUNK_OFF    64      // ushort offset of chunk start (row 0, col 32)

#define ROWS_W   30                      // stored rows per wave (6 whole polys)
#define WAVES_B  4
#define NWAVES2  ((M_ROWS+ROWS_W-1)/ROWS_W)     // 3334
#define NBLK2    ((NWAVES2+WAVES_B-1)/WAVES_B)  // 834

typedef __attribute__((ext_vector_type(8))) short short8;
typedef __attribute__((ext_vector_type(4))) float f32x4;

__device__ inline unsigned short f2bf(float f) {
    union { float f; unsigned u; } v; v.f = f;
    return (unsigned short)((v.u + 0x7fffu + ((v.u >> 16) & 1u)) >> 16);
}

// ---- kernel 1: w2 pack (blocks [0,308)) + per-wave poly prep (rest) ----
__global__ __launch_bounds__(256) void prep_pack(
    const float* __restrict__ geoms, const int* __restrict__ lengths,
    const float* __restrict__ w1, const float* __restrict__ b1,
    const float* __restrict__ w2,
    const int* __restrict__ roi_w, const int* __restrict__ roi_h,
    unsigned short* __restrict__ Wp, float* __restrict__ out)
{
    if (blockIdx.x < NPACK_BLK) {
        int i = blockIdx.x * 256 + threadIdx.x;
        if (i < WP_ELEMS) {
            int j    = i & 7;
            int lane = (i >> 3) & 63;
            int grp  = i >> 9;               // ks*14 + nt
            int nt   = grp % NTILES;
            int ks   = grp / NTILES;
            int k    = ks * 32 + (lane >> 4) * 8 + j;   // k = dk*112 + c
            int n    = nt * 16 + (lane & 15);
            float v = 0.f;
            if (k < 336) {
                int dk = k / C_MID, c = k - dk * C_MID;
                v = w2[(n * C_MID + c) * 3 + dk];
            }
            Wp[i] = f2bf(v);
        }
        return;
    }

    const int poly = (blockIdx.x - NPACK_BLK) * POLY_PER_BLK + (threadIdx.x >> 6);
    const int lane = threadIdx.x & 63;
    if (poly >= K_POLY) return;

    // ---- load polyline: one point per lane ----
    const float* gp = geoms + (size_t)poly * (PMAX * 2);
    float px = 0.f, py = 0.f;
    if (lane < PMAX) { float2 p = ((const float2*)gp)[lane]; px = p.x; py = p.y; }
    const int L = lengths[poly];

    // ---- per-lane segment length, shfl prefix-scan for cum ----
    float nx = __shfl(px, lane + 1);
    float ny = __shfl(py, lane + 1);
    float seg = 0.f;
    if (lane < L - 1 && lane < PMAX - 1) {
        float dx = nx - px, dy = ny - py;
        float sq = dx * dx + dy * dy;
        seg = (sq > 0.f) ? sqrtf(sq) : 0.f;
    }
    float incl = seg;
    #pragma unroll
    for (int d = 1; d < 32; d <<= 1) {
        float v = __shfl_up(incl, d, 32);
        if ((lane & 31) >= d) incl += v;
    }
    float cum = __shfl_up(incl, 1, 32);   // cum[i] = sum seg[0..i-1]
    if ((lane & 31) == 0) cum = 0.f;
    const float total = __shfl(incl, PMAX - 2);

    const float roiw = (float)roi_w[0], roih = (float)roi_h[0];
    const float halfx = roiw * 0.5f, halfy = roih * 0.5f;
    const bool degen = total < 1e-6f;
    const float x0g = __shfl(px, 0), y0g = __shfl(py, 0);

    // ---- resample 5 points, wave-uniform via ballot searchsorted ----
    float bxv[NUM_PTS], byv[NUM_PTS];
    #pragma unroll
    for (int j = 0; j < NUM_PTS; ++j) {
        float tj = total * (0.25f * (float)j);
        unsigned long long mlt = __ballot(lane < PMAX && cum < tj);
        int idx = (int)__popcll(mlt);     // first i with cum[i] >= tj
        idx = max(1, min(idx, L - 1));
        float c1 = __shfl(cum, idx - 1);
        float s1 = __shfl(seg, idx - 1);
        float ax = __shfl(px, idx - 1), ay = __shfl(py, idx - 1);
        float bx2 = __shfl(px, idx),    by2 = __shfl(py, idx);
        float tt = (tj - c1) / (s1 + 1e-8f);
        float fx = degen ? x0g : ax + tt * (bx2 - ax);
        float fy = degen ? y0g : ay + tt * (by2 - ay);
        bxv[j] = (fx + halfx) / roiw;
        byv[j] = (fy + halfy) / roih;
    }
    if (lane == 0) {
        float* co = out + (size_t)M_ROWS * GEO_DIM + (size_t)poly * (NUM_PTS * 2);
        #pragma unroll
        for (int j = 0; j < NUM_PTS; ++j) { co[2 * j] = bxv[j]; co[2 * j + 1] = byv[j]; }
    }

    // ---- A chunk: zero halo slots + K-pad, then conv1 (one channel/lane) ----
    unsigned short* chunk = (unsigned short*)out + (size_t)poly * CHUNK_STRIDE + CHUNK_OFF;
    unsigned int* cz = (unsigned int*)chunk;
    if (lane < 56) cz[lane] = 0u;          // slot 0 (elems 0..111)
    cz[336 + lane] = 0u;                   // elems 672..799 (slot 6 + K-pad)

    #pragma unroll
    for (int it = 0; it < 2; ++it) {
        int c = it * 64 + lane;
        if (c < C_MID) {
            const float* w = w1 + c * 6;
            float w0 = w[0], wa = w[1], wb = w[2], w3 = w[3], w4 = w[4], w5 = w[5];
            float bb = b1[c];
            #pragma unroll
            for (int p = 0; p < NUM_PTS; ++p) {
                float acc = bb + bxv[p] * wa + byv[p] * w4;
                if (p > 0)           acc += bxv[p - 1] * w0 + byv[p - 1] * w3;
                if (p < NUM_PTS - 1) acc += bxv[p + 1] * wb + byv[p + 1] * w5;
                chunk[(p + 1) * C_MID + c] = f2bf(fmaxf(acc, 0.f));
            }
        }
    }
}

// ---- kernel 2: barrier-free MFMA conv2 (B direct from L2) + PE + LN + store ----
__global__ __launch_bounds__(256, 2) void gemm2(
    const unsigned short* __restrict__ Wp,
    const float* __restrict__ b2, const float* __restrict__ gamma,
    const float* __restrict__ beta, float* __restrict__ out)
{
    const int t = threadIdx.x, lane = t & 63, wave = t >> 6;
    const int quad = lane >> 4, m = lane & 15;
    const int rw = (blockIdx.x * WAVES_B + wave) * ROWS_W;

    // A frag bases (rows rw+m and rw+16+m; clamped rows' C output never stored)
    int r0 = min(rw + m, M_ROWS - 1);
    int r1 = min(rw + 16 + m, M_ROWS - 1);
    int poly0 = r0 / 5, p0 = r0 - poly0 * 5;
    int poly1 = r1 / 5, p1 = r1 - poly1 * 5;
    const unsigned short* A = (const unsigned short*)out;
    const unsigned short* Ab0 = A + (size_t)poly0 * CHUNK_STRIDE + CHUNK_OFF + p0 * C_MID + quad * 8;
    const unsigned short* Ab1 = A + (size_t)poly1 * CHUNK_STRIDE + CHUNK_OFF + p1 * C_MID + quad * 8;

    // per-lane B pointer: frag (ks,nt) lives at Bl[(ks*NTILES+nt)*64] (short8 units)
    const short8* Bl = (const short8*)(Wp + lane * 8);

    f32x4 acc0[NTILES], acc1[NTILES];
    #pragma unroll
    for (int nt = 0; nt < NTILES; ++nt)
        #pragma unroll
        for (int i = 0; i < 4; ++i) { acc0[nt][i] = 0.f; acc1[nt][i] = 0.f; }

    #pragma unroll
    for (int ks = 0; ks < KSTEPS; ++ks) {
        short8 a0 = *(const short8*)(Ab0 + ks * 32);
        short8 a1 = *(const short8*)(Ab1 + ks * 32);
        short8 b[NTILES];
        #pragma unroll
        for (int nt = 0; nt < NTILES; ++nt) b[nt] = Bl[(ks * NTILES + nt) * 64];
        __builtin_amdgcn_s_setprio(1);
        #pragma unroll
        for (int nt = 0; nt < NTILES; ++nt) {
            acc0[nt] = __builtin_amdgcn_mfma_f32_16x16x32_bf16(a0, b[nt], acc0[nt], 0, 0, 0);
            acc1[nt] = __builtin_amdgcn_mfma_f32_16x16x32_bf16(a1, b[nt], acc1[nt], 0, 0, 0);
        }
        __builtin_amdgcn_s_setprio(0);
    }

    // ---- PE: cols 0..31 for rows rw..rw+29 (coords from prep) ----
    {
        const float* cptr = out + (size_t)M_ROWS * GEO_DIM;
        const int col = lane & 31;
        const int d = col >> 4, isc = (col >> 3) & 1, fr = col & 7;
        const float pef = (float)(1 << fr) * 3.14159265358979323846f;
        #pragma unroll
        for (int it = 0; it < 15; ++it) {
            int r = rw + it * 2 + (lane >> 5);
            if (r < M_ROWS) {
                float x = cptr[(size_t)r * 2 + d];
                float arg = x * pef;
                out[(size_t)r * GEO_DIM + col] = isc ? __cosf(arg) : __sinf(arg);
            }
        }
    }

    // ---- bias + ReLU + in-wave LayerNorm + store cols 32..255 ----
    float bias[NTILES], gm[NTILES], bt[NTILES];
    #pragma unroll
    for (int nt = 0; nt < NTILES; ++nt) {
        int col = nt * 16 + m;
        bias[nt] = b2[col]; gm[nt] = gamma[col]; bt[nt] = beta[col];
    }

    auto epilogue = [&](f32x4 (&acc)[NTILES], int g) {
        #pragma unroll
        for (int i = 0; i < 4; ++i) {
            float s = 0.f, q = 0.f;
            #pragma unroll
            for (int nt = 0; nt < NTILES; ++nt) {
                float v = fmaxf(acc[nt][i] + bias[nt], 0.f);
                acc[nt][i] = v;
                s += v; q += v * v;
            }
            #pragma unroll
            for (int mk = 8; mk >= 1; mk >>= 1) {
                s += __shfl_xor(s, mk, 64);
                q += __shfl_xor(q, mk, 64);
            }
            float mu  = s * (1.f / C_OUT);
            float var = fmaxf(q * (1.f / C_OUT) - mu * mu, 0.f);
            float rs  = rsqrtf(var + 1e-5f);
            int r = rw + g * 16 + quad * 4 + i;
            // rows rw+30/31 (g==1, quad==3, i>=2) are the neighbor-poly garbage frag
            if (r < M_ROWS && !(g == 1 && quad == 3 && i >= 2)) {
                size_t ob = (size_t)r * GEO_DIM + PE_DIM + m;
                #pragma unroll
                for (int nt = 0; nt < NTILES; ++nt)
                    out[ob + nt * 16] = (acc[nt][i] - mu) * rs * gm[nt] + bt[nt];
            }
        }
    };
    epilogue(acc0, 0);
    epilogue(acc1, 1);
}

extern "C" void kernel_launch(void* const* d_in, const int* in_sizes, int n_in,
                              void* d_out, int out_size, void* d_ws, size_t ws_size,
                              hipStream_t stream) {
    const float* geoms   = (const float*)d_in[0];
    const int*   lengths = (const int*)d_in[1];
    const float* w1      = (const float*)d_in[2];
    const float* b1      = (const float*)d_in[3];
    const float* w2      = (const float*)d_in[4];
    const float* b2      = (const float*)d_in[5];
    const float* gamma   = (const float*)d_in[6];
    const float* beta    = (const float*)d_in[7];
    const int*   roi_w   = (const int*)d_in[8];
    const int*   roi_h   = (const int*)d_in[9];
    float* out = (float*)d_out;
    unsigned short* Wp = (unsigned short*)d_ws;   // 157696 B

    hipLaunchKernelGGL(prep_pack, dim3(NPACK_BLK + NPREP_BLK), dim3(256), 0, stream,
                       geoms, lengths, w1, b1, w2, roi_w, roi_h, Wp, out);
    hipLaunchKernelGGL(gemm2, dim3(NBLK2), dim3(256), 0, stream, Wp, b2, gamma, beta, out);
}

// Round 3
// 166.319 us; speedup vs baseline: 1.1703x; 1.0709x over previous
//
#include <hip/hip_runtime.h>
#include <math.h>

#define K_POLY   20000
#define PMAX     30
#define NUM_PTS  5
#define C_MID    112
#define C_OUT    224
#define PE_DIM   32
#define GEO_DIM  256
#define M_ROWS   (K_POLY*NUM_PTS)        // 100000

#define NTILES   14                      // 224/16 n-tiles
#define KSTEPS   11                      // K padded 336 -> 352 = 11*32
#define WP_ELEMS (KSTEPS*NTILES*64*8)    // 78848 bf16 = 157696 B
#define NPACK_BLK ((WP_ELEMS+255)/256)   // 308
#define POLY_PER_BLK 4
#define NPREP_BLK ((K_POLY+POLY_PER_BLK-1)/POLY_PER_BLK)  // 5000

// in-place A storage: per-poly chunk of 7*112 bf16 (+16 pad) living in the
// cols-32..255 region of that poly's 5 output rows (overwritten later by LN)
#define CHUNK_STRIDE 2560    // ushort elems per poly block (5 rows * 256 * 2)
#define CHUNK_OFF    64      // ushort offset of chunk start (row 0, col 32)

#define ROWS_W   30                      // stored rows per wave-unit (6 whole polys)
#define NUNITS   ((M_ROWS+ROWS_W-1)/ROWS_W)     // 3334
#define WAVES2_B 8                       // 512-thread blocks
#define NBLK2    256                     // 1 block/CU (154 KB LDS)
#define TOTW2    (NBLK2*WAVES2_B)        // 2048 waves

typedef __attribute__((ext_vector_type(8))) short short8;
typedef __attribute__((ext_vector_type(4))) float f32x4;

__device__ inline unsigned short f2bf(float f) {
    union { float f; unsigned u; } v; v.f = f;
    return (unsigned short)((v.u + 0x7fffu + ((v.u >> 16) & 1u)) >> 16);
}

#define GLDS(gp, lp) __builtin_amdgcn_global_load_lds( \
    (const __attribute__((address_space(1))) void*)(gp), \
    (__attribute__((address_space(3))) void*)(lp), 16, 0, 0)

// ---- kernel 1: w2 pack (blocks [0,308)) + per-wave poly prep (rest) ----
__global__ __launch_bounds__(256) void prep_pack(
    const float* __restrict__ geoms, const int* __restrict__ lengths,
    const float* __restrict__ w1, const float* __restrict__ b1,
    const float* __restrict__ w2,
    const int* __restrict__ roi_w, const int* __restrict__ roi_h,
    unsigned short* __restrict__ Wp, float* __restrict__ out)
{
    if (blockIdx.x < NPACK_BLK) {
        int i = blockIdx.x * 256 + threadIdx.x;
        if (i < WP_ELEMS) {
            int j    = i & 7;
            int lane = (i >> 3) & 63;
            int grp  = i >> 9;               // ks*14 + nt
            int nt   = grp % NTILES;
            int ks   = grp / NTILES;
            int k    = ks * 32 + (lane >> 4) * 8 + j;   // k = dk*112 + c
            int n    = nt * 16 + (lane & 15);
            float v = 0.f;
            if (k < 336) {
                int dk = k / C_MID, c = k - dk * C_MID;
                v = w2[(n * C_MID + c) * 3 + dk];
            }
            Wp[i] = f2bf(v);
        }
        return;
    }

    const int poly = (blockIdx.x - NPACK_BLK) * POLY_PER_BLK + (threadIdx.x >> 6);
    const int lane = threadIdx.x & 63;
    if (poly >= K_POLY) return;

    // ---- load polyline: one point per lane ----
    const float* gp = geoms + (size_t)poly * (PMAX * 2);
    float px = 0.f, py = 0.f;
    if (lane < PMAX) { float2 p = ((const float2*)gp)[lane]; px = p.x; py = p.y; }
    const int L = lengths[poly];

    // ---- per-lane segment length, shfl prefix-scan for cum ----
    float nx = __shfl(px, lane + 1);
    float ny = __shfl(py, lane + 1);
    float seg = 0.f;
    if (lane < L - 1 && lane < PMAX - 1) {
        float dx = nx - px, dy = ny - py;
        float sq = dx * dx + dy * dy;
        seg = (sq > 0.f) ? sqrtf(sq) : 0.f;
    }
    float incl = seg;
    #pragma unroll
    for (int d = 1; d < 32; d <<= 1) {
        float v = __shfl_up(incl, d, 32);
        if ((lane & 31) >= d) incl += v;
    }
    float cum = __shfl_up(incl, 1, 32);   // cum[i] = sum seg[0..i-1]
    if ((lane & 31) == 0) cum = 0.f;
    const float total = __shfl(incl, PMAX - 2);

    const float roiw = (float)roi_w[0], roih = (float)roi_h[0];
    const float halfx = roiw * 0.5f, halfy = roih * 0.5f;
    const bool degen = total < 1e-6f;
    const float x0g = __shfl(px, 0), y0g = __shfl(py, 0);

    // ---- resample 5 points, wave-uniform via ballot searchsorted ----
    float bxv[NUM_PTS], byv[NUM_PTS];
    #pragma unroll
    for (int j = 0; j < NUM_PTS; ++j) {
        float tj = total * (0.25f * (float)j);
        unsigned long long mlt = __ballot(lane < PMAX && cum < tj);
        int idx = (int)__popcll(mlt);     // first i with cum[i] >= tj
        idx = max(1, min(idx, L - 1));
        float c1 = __shfl(cum, idx - 1);
        float s1 = __shfl(seg, idx - 1);
        float ax = __shfl(px, idx - 1), ay = __shfl(py, idx - 1);
        float bx2 = __shfl(px, idx),    by2 = __shfl(py, idx);
        float tt = (tj - c1) / (s1 + 1e-8f);
        float fx = degen ? x0g : ax + tt * (bx2 - ax);
        float fy = degen ? y0g : ay + tt * (by2 - ay);
        bxv[j] = (fx + halfx) / roiw;
        byv[j] = (fy + halfy) / roih;
    }
    if (lane == 0) {
        float* co = out + (size_t)M_ROWS * GEO_DIM + (size_t)poly * (NUM_PTS * 2);
        #pragma unroll
        for (int j = 0; j < NUM_PTS; ++j) { co[2 * j] = bxv[j]; co[2 * j + 1] = byv[j]; }
    }

    // ---- A chunk: zero halo slots + K-pad, then conv1 (one channel/lane) ----
    unsigned short* chunk = (unsigned short*)out + (size_t)poly * CHUNK_STRIDE + CHUNK_OFF;
    unsigned int* cz = (unsigned int*)chunk;
    if (lane < 56) cz[lane] = 0u;          // slot 0 (elems 0..111)
    cz[336 + lane] = 0u;                   // elems 672..799 (slot 6 + K-pad)

    #pragma unroll
    for (int it = 0; it < 2; ++it) {
        int c = it * 64 + lane;
        if (c < C_MID) {
            const float* w = w1 + c * 6;
            float w0 = w[0], wa = w[1], wb = w[2], w3 = w[3], w4 = w[4], w5 = w[5];
            float bb = b1[c];
            #pragma unroll
            for (int p = 0; p < NUM_PTS; ++p) {
                float acc = bb + bxv[p] * wa + byv[p] * w4;
                if (p > 0)           acc += bxv[p - 1] * w0 + byv[p - 1] * w3;
                if (p < NUM_PTS - 1) acc += bxv[p + 1] * wb + byv[p + 1] * w5;
                chunk[(p + 1) * C_MID + c] = f2bf(fmaxf(acc, 0.f));
            }
        }
    }
}

// ---- kernel 2: all-B-in-LDS MFMA conv2 (1 block/CU, barrier-free steady state) ----
__global__ __launch_bounds__(512, 2) void gemm2(
    const unsigned short* __restrict__ Wp,
    const float* __restrict__ b2, const float* __restrict__ gamma,
    const float* __restrict__ beta, float* __restrict__ out)
{
    __shared__ __align__(16) unsigned short s_B[WP_ELEMS];   // 157696 B

    const int t = threadIdx.x, lane = t & 63, wave = t >> 6;
    const int quad = lane >> 4, m = lane & 15;

    // ---- stage ALL of Wp into LDS (9856 x 16B chunks over 512 threads) ----
    #pragma unroll
    for (int it = 0; it < 20; ++it) {
        int idx = t + it * 512;
        if (idx < WP_ELEMS / 8)
            GLDS((const char*)Wp + (size_t)idx * 16, (char*)s_B + idx * 16);
    }
    __syncthreads();

    const unsigned short* A = (const unsigned short*)out;
    const float* cptr = out + (size_t)M_ROWS * GEO_DIM;
    const unsigned short* bl = s_B + lane * 8;   // per-lane B base; frag stride 512

    for (int u = blockIdx.x * WAVES2_B + wave; u < NUNITS; u += TOTW2) {
        const int rw = u * ROWS_W;

        // A frag bases (rows rw+m and rw+16+m; clamped rows' C output never stored)
        int r0 = min(rw + m, M_ROWS - 1);
        int r1 = min(rw + 16 + m, M_ROWS - 1);
        int poly0 = r0 / 5, p0 = r0 - poly0 * 5;
        int poly1 = r1 / 5, p1 = r1 - poly1 * 5;
        const unsigned short* Ab0 = A + (size_t)poly0 * CHUNK_STRIDE + CHUNK_OFF + p0 * C_MID + quad * 8;
        const unsigned short* Ab1 = A + (size_t)poly1 * CHUNK_STRIDE + CHUNK_OFF + p1 * C_MID + quad * 8;

        f32x4 acc0[NTILES], acc1[NTILES];
        #pragma unroll
        for (int nt = 0; nt < NTILES; ++nt)
            #pragma unroll
            for (int i = 0; i < 4; ++i) { acc0[nt][i] = 0.f; acc1[nt][i] = 0.f; }

        short8 a0 = *(const short8*)Ab0;
        short8 a1 = *(const short8*)Ab1;
        #pragma unroll
        for (int ks = 0; ks < KSTEPS; ++ks) {
            short8 a0n = a0, a1n = a1;
            if (ks < KSTEPS - 1) {
                a0n = *(const short8*)(Ab0 + (ks + 1) * 32);
                a1n = *(const short8*)(Ab1 + (ks + 1) * 32);
            }
            const unsigned short* bp = bl + ks * (NTILES * 512);
            __builtin_amdgcn_s_setprio(1);
            #pragma unroll
            for (int nt = 0; nt < NTILES; ++nt) {
                short8 b = *(const short8*)(bp + nt * 512);
                acc0[nt] = __builtin_amdgcn_mfma_f32_16x16x32_bf16(a0, b, acc0[nt], 0, 0, 0);
                acc1[nt] = __builtin_amdgcn_mfma_f32_16x16x32_bf16(a1, b, acc1[nt], 0, 0, 0);
            }
            __builtin_amdgcn_s_setprio(0);
            a0 = a0n; a1 = a1n;
        }

        // ---- PE: cols 0..31 for rows rw..rw+29 (coords from prep) ----
        {
            const int col = lane & 31;
            const int d = col >> 4, isc = (col >> 3) & 1, fr = col & 7;
            const float pef = (float)(1 << fr) * 3.14159265358979323846f;
            #pragma unroll
            for (int it = 0; it < 15; ++it) {
                int r = rw + it * 2 + (lane >> 5);
                if (r < M_ROWS) {
                    float x = cptr[(size_t)r * 2 + d];
                    float arg = x * pef;
                    out[(size_t)r * GEO_DIM + col] = isc ? __cosf(arg) : __sinf(arg);
                }
            }
        }

        // ---- bias + ReLU + in-wave LayerNorm + store cols 32..255 ----
        float bias[NTILES], gm[NTILES], bt[NTILES];
        #pragma unroll
        for (int nt = 0; nt < NTILES; ++nt) {
            int col = nt * 16 + m;
            bias[nt] = b2[col]; gm[nt] = gamma[col]; bt[nt] = beta[col];
        }

        #pragma unroll
        for (int g = 0; g < 2; ++g) {
            f32x4* acc = g ? acc1 : acc0;
            #pragma unroll
            for (int i = 0; i < 4; ++i) {
                float s = 0.f, q = 0.f;
                #pragma unroll
                for (int nt = 0; nt < NTILES; ++nt) {
                    float v = fmaxf(acc[nt][i] + bias[nt], 0.f);
                    acc[nt][i] = v;
                    s += v; q += v * v;
                }
                #pragma unroll
                for (int mk = 8; mk >= 1; mk >>= 1) {
                    s += __shfl_xor(s, mk, 64);
                    q += __shfl_xor(q, mk, 64);
                }
                float mu  = s * (1.f / C_OUT);
                float var = fmaxf(q * (1.f / C_OUT) - mu * mu, 0.f);
                float rs  = rsqrtf(var + 1e-5f);
                int r = rw + g * 16 + quad * 4 + i;
                // rows rw+30/31 (g==1, quad==3, i>=2) are the neighbor-poly garbage frag
                if (r < M_ROWS && !(g == 1 && quad == 3 && i >= 2)) {
                    size_t ob = (size_t)r * GEO_DIM + PE_DIM + m;
                    #pragma unroll
                    for (int nt = 0; nt < NTILES; ++nt)
                        out[ob + nt * 16] = (acc[nt][i] - mu) * rs * gm[nt] + bt[nt];
                }
            }
        }
    }
}

extern "C" void kernel_launch(void* const* d_in, const int* in_sizes, int n_in,
                              void* d_out, int out_size, void* d_ws, size_t ws_size,
                              hipStream_t stream) {
    const float* geoms   = (const float*)d_in[0];
    const int*   lengths = (const int*)d_in[1];
    const float* w1      = (const float*)d_in[2];
    const float* b1      = (const float*)d_in[3];
    const float* w2      = (const float*)d_in[4];
    const float* b2      = (const float*)d_in[5];
    const float* gamma   = (const float*)d_in[6];
    const float* beta    = (const float*)d_in[7];
    const int*   roi_w   = (const int*)d_in[8];
    const int*   roi_h   = (const int*)d_in[9];
    float* out = (float*)d_out;
    unsigned short* Wp = (unsigned short*)d_ws;   // 157696 B

    hipLaunchKernelGGL(prep_pack, dim3(NPACK_BLK + NPREP_BLK), dim3(256), 0, stream,
                       geoms, lengths, w1, b1, w2, roi_w, roi_h, Wp, out);
    hipLaunchKernelGGL(gemm2, dim3(NBLK2), dim3(512), 0, stream, Wp, b2, gamma, beta, out);
}